// Round 1
// 164.253 us; speedup vs baseline: 1.0076x; 1.0076x over previous
//
#include <hip/hip_runtime.h>

constexpr int Bsz   = 4096;
constexpr int Cdim  = 2048;
constexpr int Kdim  = 256;
constexpr int PROJW = 3 * Kdim;  // 768
constexpr int KSPLIT = 4;        // proj split-K factor (512-wide chunks)

typedef __attribute__((ext_vector_type(8))) short short8;     // 8 bf16 = 4 VGPR
typedef __attribute__((ext_vector_type(4))) float floatx4;    // MFMA C/D frag
typedef __attribute__((ext_vector_type(2))) float float2v;    // packed fp32 pair
typedef __attribute__((ext_vector_type(4))) _Float16 half4v;  // 8B fp16 quad

__device__ __forceinline__ unsigned short f2bf(float f) {
    unsigned int u = __float_as_uint(f);
    u += 0x7FFFu + ((u >> 16) & 1u);   // RTNE
    return (unsigned short)(u >> 16);
}

// Async global->LDS, 16B per lane; lds base wave-uniform (m104/m108).
__device__ __forceinline__ void load16(const void* g, void* lds) {
    __builtin_amdgcn_global_load_lds(
        (const __attribute__((address_space(1))) unsigned int*)g,
        (__attribute__((address_space(3))) unsigned int*)lds, 16, 0, 0);
}

// ---------------------------------------------------------------------------
// Tiled operand layout: 8 KB blocks = [128 rows][32 k] bf16 (one K-step LDS
// image).  xb2: [rt=32][kt=64][4096 shorts], Wcat2: [ct=6][kt=64][4096].
// ---------------------------------------------------------------------------

// Prep: blocks [0,4096): x fp32 -> bf16 into xb2 tiled layout, 8 floats per
// thread (32B contiguous read, 16B tiled write).  blocks [4096,6144):
// 32x32 transpose-cast; z<3 -> Wcat2 tiled; z==3: Wg -> WgT row-major.
__global__ __launch_bounds__(256) void prep_kernel(
    const float* __restrict__ x, unsigned short* __restrict__ xb2,
    const float* __restrict__ Wt, const float* __restrict__ Wp,
    const float* __restrict__ Wf, const float* __restrict__ Wg,
    unsigned short* __restrict__ Wcat2, unsigned short* __restrict__ WgT)
{
    __shared__ float tile[32][33];
    const int bid = blockIdx.x;
    if (bid < 4096) {
        const int i   = bid * 256 + threadIdx.x;  // 8-float octet index
        const int row = i >> 8;                   // 256 octets per row
        const int kg  = i & 255;                  // k = kg*8
        const float4* xv = reinterpret_cast<const float4*>(x);
        const float4 v0 = xv[2 * i];
        const float4 v1 = xv[2 * i + 1];
        short8 o;
        o[0] = (short)f2bf(v0.x); o[1] = (short)f2bf(v0.y);
        o[2] = (short)f2bf(v0.z); o[3] = (short)f2bf(v0.w);
        o[4] = (short)f2bf(v1.x); o[5] = (short)f2bf(v1.y);
        o[6] = (short)f2bf(v1.z); o[7] = (short)f2bf(v1.w);
        const size_t dst = ((size_t)(row >> 7) * 64 + (kg >> 2)) * 4096 +
                           (row & 127) * 32 + (kg & 3) * 8;
        *reinterpret_cast<short8*>(xb2 + dst) = o;
        return;
    }
    const int q = bid - 4096;
    const int z = q >> 9;            // 0..3
    const int tileId = q & 511;
    const float* __restrict__ in;
    int R, C;
    if (z < 3) {
        in = (z == 0) ? Wt : (z == 1) ? Wp : Wf;
        R = Cdim; C = Kdim;          // in [k][j]
    } else {
        in = Wg; R = Kdim; C = Cdim; // in [k][c]
    }
    const int ctiles = C / 32;
    const int c0 = (tileId % ctiles) * 32;
    const int r0 = (tileId / ctiles) * 32;
    const int tx = threadIdx.x & 31, ty = threadIdx.x >> 5;  // 32 x 8
#pragma unroll
    for (int i = ty; i < 32; i += 8)
        tile[i][tx] = in[(size_t)(r0 + i) * C + c0 + tx];
    __syncthreads();
    if (z < 3) {
#pragma unroll
        for (int i = ty; i < 32; i += 8) {
            const int cg = z * 256 + c0 + i;
            Wcat2[((size_t)(cg >> 7) * 64 + (r0 >> 5)) * 4096 +
                  (cg & 127) * 32 + tx] = f2bf(tile[tx][i]);
        }
    } else {
#pragma unroll
        for (int i = ty; i < 32; i += 8)
            WgT[(size_t)(c0 + i) * R + r0 + tx] = f2bf(tile[tx][i]);
    }
}

// ---------------------------------------------------------------------------
// proj partials: pp[z] = x[:, z*512..] @ Wcat[:, z*512..]^T, fp16 out.
// BM=BN=128, BK=32, 4 waves (2x2), wave tile 64x64, 16x16x32 MFMA.
// K-loop is a 2-phase double-buffered pipeline (guide T3-minimum): stage
// K-step kt+1 into the spare LDS buffer, compute kt from the live one, then
// one vmcnt(0) + raw s_barrier per step (no __syncthreads full-drain).
// Race check: buf[cur^1] was last ds_read at kt-1; those reads complete
// before the kt-1 barrier (lgkm wait precedes MFMA precedes barrier), so
// staging into it at kt is safe.  buf[cur]'s loads drained by the vmcnt(0)
// at the end of kt-1.
// XCD swizzle: linear block id L in [0,192) -> xcd=L&7; each XCD owns 4
// rowTiles x 6 colTiles so its xb2/Wcat2 slices stay L2-resident.
// grid (192, 4).
// ---------------------------------------------------------------------------
constexpr int RPS = 152;  // repack LDS row stride in fp16 (304 B, 16B-aligned)

__global__ __launch_bounds__(256) void proj_mfma(
    const unsigned short* __restrict__ xb2,
    const unsigned short* __restrict__ Wcat2,
    _Float16* __restrict__ pp)       // [KSPLIT][Bsz][PROJW]
{
    __shared__ __align__(16) char pool[128 * RPS * 2];  // 38912 B >= 32768 dbuf
    short* S = (short*)pool;   // shorts: A0 [0,4096) A1 [4096,8192)
                               //         B0 [8192,12288) B1 [12288,16384)

    const int tid  = threadIdx.x;
    const int lane = tid & 63;
    const int wid  = tid >> 6;
    const int wr   = wid >> 1, wc = wid & 1;

    const int L    = blockIdx.x;         // 0..191
    const int xcd  = L & 7;
    const int slot = L >> 3;             // 0..23
    const int rowTile = xcd * 4 + slot / 6;   // 0..31
    const int colTile = slot % 6;             // 0..5
    const int rowBase = rowTile * 128;
    const int colBase = colTile * 128;
    const int kz      = blockIdx.y;           // split-K chunk

    floatx4 acc[4][4] = {};

    const unsigned short* gA =
        xb2 + ((size_t)rowTile * 64 + kz * 16) * 4096 + tid * 8;
    const unsigned short* gB =
        Wcat2 + ((size_t)colTile * 64 + kz * 16) * 4096 + tid * 8;

    const int wbase = (tid & ~63) * 8;   // wave-uniform LDS offset (shorts)
    const int mrow = lane & 15;
    const int kgrp = lane >> 4;

    // prologue: stage K-step 0 into buf0
    load16(gA, S + wbase);        load16(gA + 2048, S + wbase + 2048);
    load16(gB, S + 8192 + wbase); load16(gB + 2048, S + 8192 + wbase + 2048);
    gA += 4096; gB += 4096;
    asm volatile("s_waitcnt vmcnt(0)" ::: "memory");
    __builtin_amdgcn_s_barrier();
    asm volatile("" ::: "memory");

    int cur = 0;
    for (int kt = 0; kt < 16; ++kt) {
        if (kt < 15) {                       // stage kt+1 into spare buffer
            short* An = S + (cur ^ 1) * 4096;
            short* Bn = S + 8192 + (cur ^ 1) * 4096;
            load16(gA, An + wbase);        load16(gA + 2048, An + wbase + 2048);
            load16(gB, Bn + wbase);        load16(gB + 2048, Bn + wbase + 2048);
            gA += 4096; gB += 4096;
        }
        const short* Ac = S + cur * 4096;
        const short* Bc = S + 8192 + cur * 4096;
        short8 af[4], bfr[4];
#pragma unroll
        for (int i = 0; i < 4; ++i)
            af[i]  = *(const short8*)&Ac[(wr * 64 + i * 16 + mrow) * 32 + kgrp * 8];
#pragma unroll
        for (int j = 0; j < 4; ++j)
            bfr[j] = *(const short8*)&Bc[(wc * 64 + j * 16 + mrow) * 32 + kgrp * 8];
#pragma unroll
        for (int i = 0; i < 4; ++i)
#pragma unroll
            for (int j = 0; j < 4; ++j)
                acc[i][j] = __builtin_amdgcn_mfma_f32_16x16x32_bf16(
                    af[i], bfr[j], acc[i][j], 0, 0, 0);
        asm volatile("s_waitcnt vmcnt(0)" ::: "memory");  // kt+1 loads landed
        __builtin_amdgcn_s_barrier();
        asm volatile("" ::: "memory");
        cur ^= 1;
    }

    // Repack: C/D layout col = lane&15, row = (lane>>4)*4 + reg  [m89/m91]
    _Float16* rp = (_Float16*)pool;
#pragma unroll
    for (int j = 0; j < 4; ++j) {
        const int cL = wc * 64 + j * 16 + mrow;
#pragma unroll
        for (int i = 0; i < 4; ++i)
#pragma unroll
            for (int r = 0; r < 4; ++r)
                rp[(wr * 64 + i * 16 + kgrp * 4 + r) * RPS + cL] =
                    (_Float16)acc[i][j][r];
    }
    __syncthreads();

    _Float16* __restrict__ dst = pp + (size_t)kz * Bsz * PROJW;
#pragma unroll
    for (int it = 0; it < 8; ++it) {
        const int c    = it * 256 + tid;     // 2048 16B-chunks = 128 rows x 16
        const int rowL = c >> 4;
        const int ch   = c & 15;
        const float4 v = *reinterpret_cast<const float4*>(&rp[rowL * RPS + ch * 8]);
        *reinterpret_cast<float4*>(
            &dst[(size_t)(rowBase + rowL) * PROJW + colBase + ch * 8]) = v;
    }
}

// ---------------------------------------------------------------------------
// t[b,j] = softmax_k(theta_j*phi_k) . f_k.  No max-subtraction (shift-
// invariant; |theta*phi|*log2e << 126 for this data).  One wave = one sample,
// 4 consecutive j per thread; separate phi/f LDS arrays; dual accumulators;
// rcp epilogue.
// ---------------------------------------------------------------------------
__global__ __launch_bounds__(256) void attn_kernel(
    const _Float16* __restrict__ pp,   // [KSPLIT][Bsz][PROJW]
    const float* __restrict__ bt, const float* __restrict__ bp,
    const float* __restrict__ bff,
    unsigned short* __restrict__ t)
{
    __shared__ float sphi[4][Kdim];
    __shared__ float sff[4][Kdim];

    const int tid = threadIdx.x;
    const int s   = tid >> 6;
    const int l   = tid & 63;
    const int b   = blockIdx.x * 4 + s;
    const int j0  = l * 4;
    const size_t rowOff = (size_t)b * PROJW;

    float4 th = *reinterpret_cast<const float4*>(bt + j0);
    float4 ph = *reinterpret_cast<const float4*>(bp + j0);
    float4 fv = *reinterpret_cast<const float4*>(bff + j0);
#pragma unroll
    for (int z = 0; z < KSPLIT; ++z) {
        const _Float16* __restrict__ r = pp + (size_t)z * Bsz * PROJW + rowOff;
        half4v a = *reinterpret_cast<const half4v*>(r + j0);
        half4v c = *reinterpret_cast<const half4v*>(r + Kdim + j0);
        half4v d = *reinterpret_cast<const half4v*>(r + 2 * Kdim + j0);
        th.x += (float)a.x; th.y += (float)a.y; th.z += (float)a.z; th.w += (float)a.w;
        ph.x += (float)c.x; ph.y += (float)c.y; ph.z += (float)c.z; ph.w += (float)c.w;
        fv.x += (float)d.x; fv.y += (float)d.y; fv.z += (float)d.z; fv.w += (float)d.w;
    }
    const float tl[4] = {th.x * 1.44269504f, th.y * 1.44269504f,
                         th.z * 1.44269504f, th.w * 1.44269504f};
    *reinterpret_cast<float4*>(&sphi[s][j0]) = ph;
    *reinterpret_cast<float4*>(&sff[s][j0])  = fv;
    __syncthreads();

    float2v sa[4][2] = {}, na[4][2] = {};
    const float4* __restrict__ sp  = reinterpret_cast<const float4*>(sphi[s]);
    const float4* __restrict__ sfp = reinterpret_cast<const float4*>(sff[s]);
#pragma unroll 4
    for (int p = 0; p < Kdim / 4; ++p) {
        const float4 ph4 = sp[p];    // broadcast LDS b128
        const float4 ff4 = sfp[p];
        const float2v p01 = {ph4.x, ph4.y};
        const float2v p23 = {ph4.z, ph4.w};
        const float2v f01 = {ff4.x, ff4.y};
        const float2v f23 = {ff4.z, ff4.w};
#pragma unroll
        for (int i = 0; i < 4; ++i) {
            const float2v a01 = tl[i] * p01;  // v_pk_mul_f32
            const float2v a23 = tl[i] * p23;
            float2v e01, e23;
            e01.x = __builtin_amdgcn_exp2f(a01.x);
            e01.y = __builtin_amdgcn_exp2f(a01.y);
            e23.x = __builtin_amdgcn_exp2f(a23.x);
            e23.y = __builtin_amdgcn_exp2f(a23.y);
            sa[i][0] += e01;
            sa[i][1] += e23;
            na[i][0] += e01 * f01;            // v_pk_fma_f32
            na[i][1] += e23 * f23;
        }
    }
    ushort4 o;
    unsigned short* op = &o.x;
#pragma unroll
    for (int i = 0; i < 4; ++i) {
        const float den = sa[i][0].x + sa[i][0].y + sa[i][1].x + sa[i][1].y;
        const float num = na[i][0].x + na[i][0].y + na[i][1].x + na[i][1].y;
        op[i] = f2bf(num * __builtin_amdgcn_rcpf(den));
    }
    *reinterpret_cast<ushort4*>(t + (size_t)b * Kdim + j0) = o;
}

// ---------------------------------------------------------------------------
// out = x + t @ Wg + bg.  BM=BN=128, BK=32, 8 K-steps, 16x16x32 MFMA.
// Same 2-phase double-buffered K-loop as proj_mfma.  fp32 x residual.
// Epilogue: two 128x64 fp32 LDS half-tiles -> float4 stores.  grid (32, 16).
// ---------------------------------------------------------------------------
constexpr int OPS = 68;  // out repack LDS row stride in dwords (272 B)

__global__ __launch_bounds__(256) void out_mfma(
    const unsigned short* __restrict__ tb,
    const unsigned short* __restrict__ WgT,
    const float* __restrict__ bg,
    const float* __restrict__ x,
    float* __restrict__ out)
{
    __shared__ __align__(16) char pool[128 * OPS * 4];  // 34816 B >= 32768 dbuf
    short* S = (short*)pool;   // shorts: A0 A1 B0 B1, 4096 each

    const int tid  = threadIdx.x;
    const int lane = tid & 63;
    const int wid  = tid >> 6;
    const int wr   = wid >> 1, wc = wid & 1;
    const int rowBase = blockIdx.x * 128;
    const int colBase = blockIdx.y * 128;

    floatx4 acc[4][4] = {};

    const unsigned short* gA0 = tb  + (size_t)(rowBase + (tid >> 2)) * Kdim + (tid & 3) * 8;
    const unsigned short* gA1 = tb  + (size_t)(rowBase + 64 + (tid >> 2)) * Kdim + (tid & 3) * 8;
    const unsigned short* gB0 = WgT + (size_t)(colBase + (tid >> 2)) * Kdim + (tid & 3) * 8;
    const unsigned short* gB1 = WgT + (size_t)(colBase + 64 + (tid >> 2)) * Kdim + (tid & 3) * 8;

    const int wbase = (tid & ~63) * 8;
    const int mrow = lane & 15;
    const int kgrp = lane >> 4;

    // prologue: stage K-step 0 into buf0
    load16(gA0, S + wbase);        load16(gA1, S + wbase + 2048);
    load16(gB0, S + 8192 + wbase); load16(gB1, S + 8192 + wbase + 2048);
    gA0 += 32; gA1 += 32; gB0 += 32; gB1 += 32;
    asm volatile("s_waitcnt vmcnt(0)" ::: "memory");
    __builtin_amdgcn_s_barrier();
    asm volatile("" ::: "memory");

    int cur = 0;
    for (int kt = 0; kt < 8; ++kt) {
        if (kt < 7) {
            short* An = S + (cur ^ 1) * 4096;
            short* Bn = S + 8192 + (cur ^ 1) * 4096;
            load16(gA0, An + wbase);        load16(gA1, An + wbase + 2048);
            load16(gB0, Bn + wbase);        load16(gB1, Bn + wbase + 2048);
            gA0 += 32; gA1 += 32; gB0 += 32; gB1 += 32;
        }
        const short* Ac = S + cur * 4096;
        const short* Bc = S + 8192 + cur * 4096;
        short8 af[4], bfr[4];
#pragma unroll
        for (int i = 0; i < 4; ++i)
            af[i]  = *(const short8*)&Ac[(wr * 64 + i * 16 + mrow) * 32 + kgrp * 8];
#pragma unroll
        for (int j = 0; j < 4; ++j)
            bfr[j] = *(const short8*)&Bc[(wc * 64 + j * 16 + mrow) * 32 + kgrp * 8];
#pragma unroll
        for (int i = 0; i < 4; ++i)
#pragma unroll
            for (int j = 0; j < 4; ++j)
                acc[i][j] = __builtin_amdgcn_mfma_f32_16x16x32_bf16(
                    af[i], bfr[j], acc[i][j], 0, 0, 0);
        asm volatile("s_waitcnt vmcnt(0)" ::: "memory");
        __builtin_amdgcn_s_barrier();
        asm volatile("" ::: "memory");
        cur ^= 1;
    }

    float* rp = (float*)pool;
#pragma unroll
    for (int h = 0; h < 2; ++h) {
        if (wc == h) {     // this wave's cols live in half h
#pragma unroll
            for (int j = 0; j < 4; ++j) {
                const int cL = j * 16 + mrow;
#pragma unroll
                for (int i = 0; i < 4; ++i)
#pragma unroll
                    for (int r = 0; r < 4; ++r)
                        rp[(wr * 64 + i * 16 + kgrp * 4 + r) * OPS + cL] =
                            acc[i][j][r];
            }
        }
        __syncthreads();
#pragma unroll
        for (int it = 0; it < 8; ++it) {
            const int c    = it * 256 + tid;   // 2048 chunks = 128 rows x 16
            const int rowL = c >> 4;
            const int ch   = c & 15;           // 16 x 4 floats = 64 cols
            const float4 v = *reinterpret_cast<const float4*>(&rp[rowL * OPS + ch * 4]);
            const int colG = colBase + h * 64 + ch * 4;
            const size_t g = (size_t)(rowBase + rowL) * Cdim + colG;
            const float4 bgv = *reinterpret_cast<const float4*>(bg + colG);
            const float4 xv  = *reinterpret_cast<const float4*>(x + g);
            float4 o;
            o.x = v.x + bgv.x + xv.x;
            o.y = v.y + bgv.y + xv.y;
            o.z = v.z + bgv.z + xv.z;
            o.w = v.w + bgv.w + xv.w;
            *reinterpret_cast<float4*>(out + g) = o;
        }
        __syncthreads();   // h=0 reads done before h=1 overwrites
    }
}

extern "C" void kernel_launch(void* const* d_in, const int* in_sizes, int n_in,
                              void* d_out, int out_size, void* d_ws, size_t ws_size,
                              hipStream_t stream) {
    const float* x  = (const float*)d_in[0];
    const float* Wt = (const float*)d_in[1];
    const float* bt = (const float*)d_in[2];
    const float* Wp = (const float*)d_in[3];
    const float* bp = (const float*)d_in[4];
    const float* Wf = (const float*)d_in[5];
    const float* bf = (const float*)d_in[6];
    const float* Wg = (const float*)d_in[7];
    const float* bg = (const float*)d_in[8];
    float* out = (float*)d_out;

    char* w = (char*)d_ws;
    _Float16*       pp    = (_Float16*)w;                     // 4*4096*768*2 = 25,165,824
    unsigned short* xb2   = (unsigned short*)(w + 25165824);  // 16,777,216
    unsigned short* Wcat2 = (unsigned short*)(w + 41943040);  //  3,145,728
    unsigned short* WgT   = (unsigned short*)(w + 45088768);  //  1,048,576
    unsigned short* tb    = (unsigned short*)(w + 46137344);  //  2,097,152

    prep_kernel<<<6144, 256, 0, stream>>>(x, xb2, Wt, Wp, Wf, Wg, Wcat2, WgT);
    proj_mfma<<<dim3(192, KSPLIT), 256, 0, stream>>>(xb2, Wcat2, pp);
    attn_kernel<<<Bsz / 4, 256, 0, stream>>>(pp, bt, bp, bf, tb);
    out_mfma<<<dim3(Bsz / 128, Cdim / 128), 256, 0, stream>>>(tb, WgT, bg, x, out);
}